// Round 8
// baseline (30.141 us; speedup 1.0000x reference)
//
#include <hip/hip_runtime.h>
#include <math.h>

#define NEXP 16
#define BLOCK 256

typedef float f32x2 __attribute__((ext_vector_type(2)));

__global__ __launch_bounds__(BLOCK) void sparsemixer_kernel(
    const float* __restrict__ logits, float* __restrict__ out, int n_tok) {
    int t = blockIdx.x * BLOCK + threadIdx.x;
    if (t >= n_tok) return;

    // Load the 16-logit row into registers (4 x float4 = 64B per lane, coalesced).
    float x[NEXP];
    const float4* row = reinterpret_cast<const float4*>(logits + (size_t)t * NEXP);
#pragma unroll
    for (int q = 0; q < 4; ++q) {
        float4 v = row[q];
        x[4 * q + 0] = v.x;
        x[4 * q + 1] = v.y;
        x[4 * q + 2] = v.z;
        x[4 * q + 3] = v.w;
    }

    // Single-scan top-2 with first-index tie semantics (strict >).
    float m0 = x[0], m1 = -INFINITY;
    int mi0 = 0, mi1 = 0;
#pragma unroll
    for (int j = 1; j < NEXP; ++j) {
        float v = x[j];
        if (v > m0) { m1 = m0; mi1 = mi0; m0 = v; mi0 = j; }
        else if (v > m1) { m1 = v; mi1 = j; }
    }

    // Shared-exp masked softmax denominators (R4/R6 structure), now in packed
    // fp32 pairs (v_pk_add/mul_f32). Bit-identical to R6:
    //   u0 = fl(m0-v) (pk_sub, IEEE per half)
    //   exp arg: fl(u0 * (-log2e)) == fl((v-m0)*log2e)  [negation exact]
    //   masks:  u0 > th0 / u1 > th1  (same fp values as R6 fast path)
    //   accumulators: f32x2 halves == R6's even/odd split, same grouping.
    // Fast path requires m1 >= 0 (proof in R5). Slow path = exact R4 form.
    float sum0, sum1;
    if (m1 >= 0.0f) {
        const float th0 = 0.02f * m0;
        const float th1 = 0.02f * m1;
        const f32x2 m0v = {m0, m0};
        const f32x2 m1v = {m1, m1};
        const f32x2 nl2e = {-1.4426950408889634f, -1.4426950408889634f};
        f32x2 s0 = {0.f, 0.f}, s1 = {0.f, 0.f};
#pragma unroll
        for (int p = 0; p < NEXP / 2; ++p) {
            f32x2 v = {x[2 * p], x[2 * p + 1]};
            f32x2 u0 = m0v - v;            // pk_sub
            f32x2 u1 = m1v - v;            // pk_sub
            f32x2 ein = u0 * nl2e;         // pk_mul: (v-m0)*log2e bitwise
            float e0 = __builtin_amdgcn_exp2f(ein.x);   // v_exp_f32
            float e1 = __builtin_amdgcn_exp2f(ein.y);
            f32x2 a0 = {(u0.x > th0) ? 0.f : e0, (u0.y > th0) ? 0.f : e1};
            f32x2 a1 = {(u1.x > th1) ? 0.f : e0, (u1.y > th1) ? 0.f : e1};
            s0 += a0;                      // pk_add
            s1 += a1;                      // pk_add
        }
        sum0 = s0.x + s0.y;
        sum1 = (s1.x + s1.y) - 1.0f;       // remove mi0's exact exp(0)=1 term
    } else {
        float s0a = 0.f, s0b = 0.f, s1a = 0.f, s1b = 0.f;
#pragma unroll
        for (int j = 0; j < NEXP; ++j) {
            float v = x[j];
            float ev = __expf(v - m0);
            float d0 = fmaxf(fabsf(v), m0);
            bool masked0 = (m0 - v) > 0.02f * d0;
            float d1 = fmaxf(fabsf(v), m1);
            bool masked1 = (m1 - v) > 0.02f * d1;
            if (j & 1) {
                s0b += masked0 ? 0.f : ev;
                s1b += masked1 ? 0.f : ev;
            } else {
                s0a += masked0 ? 0.f : ev;
                s1a += masked1 ? 0.f : ev;
            }
        }
        sum0 = s0a + s0b;
        sum1 = (s1a + s1b) - 1.0f;
    }

    float v0 = __builtin_amdgcn_rcpf(sum0);
    float v1 = __expf(m1 - m0) * __builtin_amdgcn_rcpf(sum1);

    // Outputs: [N,2] indices (as float), then [N,2] values.
    float2* oidx = reinterpret_cast<float2*>(out);
    float2* oval = reinterpret_cast<float2*>(out) + n_tok;
    oidx[t] = make_float2((float)mi0, (float)mi1);
    oval[t] = make_float2(v0, v1);
}

extern "C" void kernel_launch(void* const* d_in, const int* in_sizes, int n_in,
                              void* d_out, int out_size, void* d_ws, size_t ws_size,
                              hipStream_t stream) {
    const float* logits = (const float*)d_in[0];
    float* out = (float*)d_out;
    int n_tok = in_sizes[0] / NEXP;
    int grid = (n_tok + BLOCK - 1) / BLOCK;
    sparsemixer_kernel<<<grid, BLOCK, 0, stream>>>(logits, out, n_tok);
}